// Round 6
// baseline (556.314 us; speedup 1.0000x reference)
//
#include <hip/hip_runtime.h>
#include <hip/hip_bf16.h>

#define T_STEPS 24
#define NB      512
#define HID     128
#define INDIM   64
#define BN      16384

typedef __bf16 bf16_t;
typedef __bf16 bf16x8 __attribute__((ext_vector_type(8)));
typedef float  f32x16 __attribute__((ext_vector_type(16)));

__device__ __forceinline__ float sigm_(float x)  { return 1.f / (1.f + __expf(-x)); }
__device__ __forceinline__ float tanh_(float x)  { float e = __expf(-2.f * x); return (1.f - e) / (1.f + e); }

#define MF(a, b, c) __builtin_amdgcn_mfma_f32_32x32x16_bf16((a), (b), (c), 0, 0, 0)

// lgkmcnt-only barrier: LDS writes visible, vmem loads stay in flight.
#define BARRIER_LDS() do { \
    asm volatile("s_waitcnt lgkmcnt(0)" ::: "memory"); \
    __builtin_amdgcn_s_barrier(); \
    __builtin_amdgcn_sched_barrier(0); \
} while (0)

// ---------------------------------------------------------------------------
// Pack kernel (identical to R5, proven). Frag = [64 lanes][8 bf16] = 512 elems.
//  Wrz [8ct][16ks]: cols 0..255 = [r|z], K=256 = [emb(128)|h(128)]
//  Win [4ct][8ks]:  i_n rows of Wih (256..383), K=128 (emb)
//  Whn [4ct][8ks]:  h_n rows of Whh (256..383), K=128 (h)
//  WmP [4ct][4ks]:  W_mlp, K=64 (x)
//  bc  [512] f32:   [0..255]=bih+bhh (rz), [256..383]=bih_n, [384..511]=bhh_n
// ---------------------------------------------------------------------------
__global__ void pack_kernel(const float* __restrict__ Wm,
                            const float* __restrict__ Wih, const float* __restrict__ Whh,
                            const float* __restrict__ bih, const float* __restrict__ bhh,
                            bf16_t* __restrict__ Wrz, bf16_t* __restrict__ Win,
                            bf16_t* __restrict__ Whn, bf16_t* __restrict__ WmP,
                            float* __restrict__ bc)
{
    int tid = blockIdx.x * 256 + threadIdx.x;
    if (tid < 65536) {                         // Wrz
        int e = tid & 7, l = (tid >> 3) & 63, ks = (tid >> 9) & 15, ct = tid >> 13;
        int col = ct * 32 + (l & 31);
        int k   = ks * 16 + ((l >> 5) << 3) + e;
        float v = (k < 128) ? Wih[col * HID + k] : Whh[col * HID + (k - 128)];
        Wrz[tid] = (bf16_t)v;
    } else if (tid < 81920) {                  // Win
        int u = tid - 65536;
        int e = u & 7, l = (u >> 3) & 63, ks = (u >> 9) & 7, ct = u >> 12;
        int col = ct * 32 + (l & 31);
        int k   = ks * 16 + ((l >> 5) << 3) + e;
        Win[u] = (bf16_t)Wih[(256 + col) * HID + k];
    } else if (tid < 98304) {                  // Whn
        int u = tid - 81920;
        int e = u & 7, l = (u >> 3) & 63, ks = (u >> 9) & 7, ct = u >> 12;
        int col = ct * 32 + (l & 31);
        int k   = ks * 16 + ((l >> 5) << 3) + e;
        Whn[u] = (bf16_t)Whh[(256 + col) * HID + k];
    } else if (tid < 106496) {                 // WmP
        int u = tid - 98304;
        int e = u & 7, l = (u >> 3) & 63, ks = (u >> 9) & 3, ct = u >> 11;
        int col = ct * 32 + (l & 31);
        int k   = ks * 16 + ((l >> 5) << 3) + e;
        WmP[u] = (bf16_t)Wm[col * INDIM + k];
    } else if (tid < 107008) {                 // bc
        int j = tid - 106496;
        float v;
        if (j < 256)      v = bih[j] + bhh[j];
        else if (j < 384) v = bih[j];
        else              v = bhh[j - 128];
        bc[j] = v;
    }
}

// ---------------------------------------------------------------------------
// Persistent GRU: 256 blocks x 512 threads (8 waves, 2/SIMD), 64 rows/block.
// Same math/indexing as R5; scheduling reworked: depth-3 Wrz register
// prefetch, x(t+1) register prefetch, lgkmcnt-only barriers.
// ---------------------------------------------------------------------------
__global__ __launch_bounds__(512, 2) void gru_all(
    const float*  __restrict__ x, float* __restrict__ out,
    const bf16_t* __restrict__ Wrz, const bf16_t* __restrict__ Win,
    const bf16_t* __restrict__ Whn, const bf16_t* __restrict__ WmP,
    const float*  __restrict__ bc,  const float* __restrict__ bm)
{
    __shared__ __align__(16) char WinS[32768];
    __shared__ __align__(16) char WhnS[32768];
    __shared__ __align__(16) char WmPS[16384];
    __shared__ __align__(16) char es  [16384];
    __shared__ __align__(16) char hs0 [16384], hs1[16384];

    const int tid = threadIdx.x;          // 0..511
    const int l   = tid & 63;
    const int w   = tid >> 6;             // 0..7
    const int rt  = w >> 2;               // rowtile 0/1
    const int ct  = w & 3;                // gate coltile
    const int r0  = blockIdx.x * 64;
    const int b   = r0 >> 9;
    const int n0  = r0 & (NB - 1);

    const int lane31 = l & 31;
    const int hi     = l >> 5;
    const int rA     = rt * 32 + lane31;
    const int sw0    = (lane31 & 15) << 4;
    const int jh     = ct * 32 + lane31;

    // per-lane x base (row rA, k-offset hi*8)
    const float* xlane = x + ((size_t)b * T_STEPS * NB + n0 + rA) * INDIM + hi * 8;

    // ---- issue x(0) prefetch FIRST (longest latency), then stage weights
    float4 px0, px1, px2, px3, px4, px5, px6, px7;
    {
        const float* xp = xlane;
        px0 = *(const float4*)(xp +  0); px1 = *(const float4*)(xp +  4);
        px2 = *(const float4*)(xp + 16); px3 = *(const float4*)(xp + 20);
        px4 = *(const float4*)(xp + 32); px5 = *(const float4*)(xp + 36);
        px6 = *(const float4*)(xp + 48); px7 = *(const float4*)(xp + 52);
    }
    {
        const uint4* s; uint4* d;
        s = (const uint4*)Win; d = (uint4*)WinS;
        for (int i = tid; i < 2048; i += 512) d[i] = s[i];
        s = (const uint4*)Whn; d = (uint4*)WhnS;
        for (int i = tid; i < 2048; i += 512) d[i] = s[i];
        s = (const uint4*)WmP; d = (uint4*)WmPS;
        for (int i = tid; i < 1024; i += 512) d[i] = s[i];
        uint4 z4 = make_uint4(0, 0, 0, 0);
        for (int i = tid; i < 1024; i += 512) ((uint4*)hs0)[i] = z4;
    }

    const float bRr = bc[jh], bRz = bc[128 + jh];
    const float bIN = bc[256 + jh], bHN = bc[384 + jh];
    const float bmv = bm[jh];

    const bf16_t* wrR = Wrz + (ct * 16) * 512 + l * 8;       // r coltile base
    const bf16_t* wrZ = Wrz + ((ct + 4) * 16) * 512 + l * 8; // z coltile base
    #define LDG(p) (*(const bf16x8*)(p))

    f32x16 h = {};

    for (int t = 0; t < T_STEPS; ++t) {
        const char* hsC = (t & 1) ? hs1 : hs0;
        char*       hsN = (t & 1) ? hs0 : hs1;
        BARRIER_LDS();                    // bar1: hs(t)/weights staged; es free

        // ---- phase A: emb tile = relu(x @ Wm^T + bm) from prefetched x regs
        f32x16 accA;
        #pragma unroll
        for (int q = 0; q < 16; ++q) accA[q] = bmv;
        #define PHA(ks, VA, VB) { \
            union { bf16_t h8[8]; bf16x8 v; } pa; \
            pa.h8[0] = (bf16_t)(VA).x; pa.h8[1] = (bf16_t)(VA).y; \
            pa.h8[2] = (bf16_t)(VA).z; pa.h8[3] = (bf16_t)(VA).w; \
            pa.h8[4] = (bf16_t)(VB).x; pa.h8[5] = (bf16_t)(VB).y; \
            pa.h8[6] = (bf16_t)(VB).z; pa.h8[7] = (bf16_t)(VB).w; \
            bf16x8 bfr = *(const bf16x8*)(WmPS + (ct * 4 + (ks)) * 1024 + l * 16); \
            accA = MF(pa.v, bfr, accA); }
        PHA(0, px0, px1) PHA(1, px2, px3) PHA(2, px4, px5) PHA(3, px6, px7)
        #undef PHA
        #pragma unroll
        for (int q = 0; q < 16; ++q) {
            int rl  = (q & 3) + ((q >> 2) << 3) + (hi << 2);
            int row = rt * 32 + rl;
            *(bf16_t*)(es + row * 256 + ((jh * 2) ^ ((rl & 15) << 4))) =
                (bf16_t)fmaxf(accA[q], 0.f);
        }

        // ---- issue x(t+1) prefetch (px regs now dead)
        {
            int tn = (t + 1 < T_STEPS) ? t + 1 : T_STEPS - 1;
            const float* xp = xlane + (size_t)tn * NB * INDIM;
            px0 = *(const float4*)(xp +  0); px1 = *(const float4*)(xp +  4);
            px2 = *(const float4*)(xp + 16); px3 = *(const float4*)(xp + 20);
            px4 = *(const float4*)(xp + 32); px5 = *(const float4*)(xp + 36);
            px6 = *(const float4*)(xp + 48); px7 = *(const float4*)(xp + 52);
        }

        // ---- Wrz prefetch prologue (kk = 0..2) — crosses the barrier in flight
        #define DECLK(k) bf16x8 re##k, rh##k, ze##k, zh##k;
        DECLK(0) DECLK(1) DECLK(2) DECLK(3) DECLK(4) DECLK(5) DECLK(6) DECLK(7)
        #undef DECLK
        #define ISSUE(k) { re##k = LDG(wrR + (k) * 512); rh##k = LDG(wrR + (8 + (k)) * 512); \
                           ze##k = LDG(wrZ + (k) * 512); zh##k = LDG(wrZ + (8 + (k)) * 512); }
        ISSUE(0) ISSUE(1) ISSUE(2)

        BARRIER_LDS();                    // bar2: es ready (vmem stays in flight)

        // ---- phase B: depth-3 pipelined over kk
        f32x16 ar, az, ai, ah;
        #pragma unroll
        for (int q = 0; q < 16; ++q) { ar[q] = bRr; az[q] = bRz; ai[q] = bIN; ah[q] = bHN; }
        #define CMP(k) { \
            int off = (((k) * 2 + hi) * 16) ^ sw0; \
            bf16x8 aE = *(const bf16x8*)(es  + rA * 256 + off); \
            bf16x8 aH = *(const bf16x8*)(hsC + rA * 256 + off); \
            bf16x8 bI = *(const bf16x8*)(WinS + (ct * 8 + (k)) * 1024 + l * 16); \
            bf16x8 bN = *(const bf16x8*)(WhnS + (ct * 8 + (k)) * 1024 + l * 16); \
            ar = MF(aE, re##k, ar); ar = MF(aH, rh##k, ar); \
            az = MF(aE, ze##k, az); az = MF(aH, zh##k, az); \
            ai = MF(aE, bI, ai);    ah = MF(aH, bN, ah); }
        CMP(0) ISSUE(3)
        CMP(1) ISSUE(4)
        CMP(2) ISSUE(5)
        CMP(3) ISSUE(6)
        CMP(4) ISSUE(7)
        CMP(5) CMP(6) CMP(7)
        #undef CMP
        #undef ISSUE

        // ---- phase C: lane-local gates + h update; write h(t+1) bf16 to hsN
        #pragma unroll
        for (int q = 0; q < 16; ++q) {
            int rl  = (q & 3) + ((q >> 2) << 3) + (hi << 2);
            int row = rt * 32 + rl;
            float r  = sigm_(ar[q]);
            float z  = sigm_(az[q]);
            float n  = tanh_(ai[q] + r * ah[q]);
            float hv = n + z * (h[q] - n);
            h[q] = hv;
            *(bf16_t*)(hsN + row * 256 + ((jh * 2) ^ ((rl & 15) << 4))) = (bf16_t)hv;
        }
    }

    // ---- final store (fp32) straight from registers
    #pragma unroll
    for (int q = 0; q < 16; ++q) {
        int rl = (q & 3) + ((q >> 2) << 3) + (hi << 2);
        out[(size_t)(r0 + rt * 32 + rl) * HID + jh] = h[q];
    }
    #undef LDG
}

// ---------------------------------------------------------------------------
extern "C" void kernel_launch(void* const* d_in, const int* in_sizes, int n_in,
                              void* d_out, int out_size, void* d_ws, size_t ws_size,
                              hipStream_t stream)
{
    const float* x   = (const float*)d_in[0];
    const float* Wm  = (const float*)d_in[1];
    const float* bm  = (const float*)d_in[2];
    const float* Wih = (const float*)d_in[3];
    const float* Whh = (const float*)d_in[4];
    const float* bih = (const float*)d_in[5];
    const float* bhh = (const float*)d_in[6];

    char* ws = (char*)d_ws;
    bf16_t* Wrz = (bf16_t*)(ws);                 // 131072 B
    bf16_t* Win = (bf16_t*)(ws + 131072);        //  32768 B
    bf16_t* Whn = (bf16_t*)(ws + 163840);        //  32768 B
    bf16_t* WmP = (bf16_t*)(ws + 196608);        //  16384 B
    float*  bcp = (float*) (ws + 212992);        //   2048 B

    pack_kernel<<<418, 256, 0, stream>>>(Wm, Wih, Whh, bih, bhh, Wrz, Win, Whn, WmP, bcp);
    gru_all<<<256, 512, 0, stream>>>(x, (float*)d_out, Wrz, Win, Whn, WmP, bcp, bm);
}

// Round 7
// 554.408 us; speedup vs baseline: 1.0034x; 1.0034x over previous
//
#include <hip/hip_runtime.h>
#include <hip/hip_bf16.h>

#define T_STEPS 24
#define NB      512
#define HID     128
#define INDIM   64
#define BN      16384

typedef __bf16 bf16_t;
typedef __bf16 bf16x8 __attribute__((ext_vector_type(8)));
typedef float  f32x16 __attribute__((ext_vector_type(16)));

__device__ __forceinline__ float sigm_(float x)  { return 1.f / (1.f + __expf(-x)); }
__device__ __forceinline__ float tanh_(float x)  { float e = __expf(-2.f * x); return (1.f - e) / (1.f + e); }

#define MF(a, b, c) __builtin_amdgcn_mfma_f32_32x32x16_bf16((a), (b), (c), 0, 0, 0)

// lgkmcnt-only barrier: LDS writes visible, vmem loads stay in flight.
#define BARRIER_LDS() do { \
    asm volatile("s_waitcnt lgkmcnt(0)" ::: "memory"); \
    __builtin_amdgcn_s_barrier(); \
    __builtin_amdgcn_sched_barrier(0); \
} while (0)

// ---------------------------------------------------------------------------
// Pack kernel (identical to R5, proven). Frag = [64 lanes][8 bf16] = 512 elems.
//  Wrz [8ct][16ks]: cols 0..255 = [r|z], K=256 = [emb(128)|h(128)]
//  Win [4ct][8ks]:  i_n rows of Wih (256..383), K=128 (emb)
//  Whn [4ct][8ks]:  h_n rows of Whh (256..383), K=128 (h)
//  WmP [4ct][4ks]:  W_mlp, K=64 (x)
//  bc  [512] f32:   [0..255]=bih+bhh (rz), [256..383]=bih_n, [384..511]=bhh_n
// ---------------------------------------------------------------------------
__global__ void pack_kernel(const float* __restrict__ Wm,
                            const float* __restrict__ Wih, const float* __restrict__ Whh,
                            const float* __restrict__ bih, const float* __restrict__ bhh,
                            bf16_t* __restrict__ Wrz, bf16_t* __restrict__ Win,
                            bf16_t* __restrict__ Whn, bf16_t* __restrict__ WmP,
                            float* __restrict__ bc)
{
    int tid = blockIdx.x * 256 + threadIdx.x;
    if (tid < 65536) {                         // Wrz
        int e = tid & 7, l = (tid >> 3) & 63, ks = (tid >> 9) & 15, ct = tid >> 13;
        int col = ct * 32 + (l & 31);
        int k   = ks * 16 + ((l >> 5) << 3) + e;
        float v = (k < 128) ? Wih[col * HID + k] : Whh[col * HID + (k - 128)];
        Wrz[tid] = (bf16_t)v;
    } else if (tid < 81920) {                  // Win
        int u = tid - 65536;
        int e = u & 7, l = (u >> 3) & 63, ks = (u >> 9) & 7, ct = u >> 12;
        int col = ct * 32 + (l & 31);
        int k   = ks * 16 + ((l >> 5) << 3) + e;
        Win[u] = (bf16_t)Wih[(256 + col) * HID + k];
    } else if (tid < 98304) {                  // Whn
        int u = tid - 81920;
        int e = u & 7, l = (u >> 3) & 63, ks = (u >> 9) & 7, ct = u >> 12;
        int col = ct * 32 + (l & 31);
        int k   = ks * 16 + ((l >> 5) << 3) + e;
        Whn[u] = (bf16_t)Whh[(256 + col) * HID + k];
    } else if (tid < 106496) {                 // WmP
        int u = tid - 98304;
        int e = u & 7, l = (u >> 3) & 63, ks = (u >> 9) & 3, ct = u >> 11;
        int col = ct * 32 + (l & 31);
        int k   = ks * 16 + ((l >> 5) << 3) + e;
        WmP[u] = (bf16_t)Wm[col * INDIM + k];
    } else if (tid < 107008) {                 // bc
        int j = tid - 106496;
        float v;
        if (j < 256)      v = bih[j] + bhh[j];
        else if (j < 384) v = bih[j];
        else              v = bhh[j - 128];
        bc[j] = v;
    }
}

// ---------------------------------------------------------------------------
// Persistent GRU: 256 blocks x 512 threads (8 waves, 2/SIMD), 64 rows/block.
// launch_bounds(512,1): LDS (128K) caps us at 1 block/CU anyway, so let the
// allocator use up to 512 VGPRs (R5/R6's 128-cap caused all the spills).
// Wrz prefetch depth-3 with 3 rotating buffers (48 VGPRs).
// ---------------------------------------------------------------------------
__global__ __launch_bounds__(512, 1) void gru_all(
    const float*  __restrict__ x, float* __restrict__ out,
    const bf16_t* __restrict__ Wrz, const bf16_t* __restrict__ Win,
    const bf16_t* __restrict__ Whn, const bf16_t* __restrict__ WmP,
    const float*  __restrict__ bc,  const float* __restrict__ bm)
{
    __shared__ __align__(16) char WinS[32768];
    __shared__ __align__(16) char WhnS[32768];
    __shared__ __align__(16) char WmPS[16384];
    __shared__ __align__(16) char es  [16384];
    __shared__ __align__(16) char hs0 [16384], hs1[16384];

    const int tid = threadIdx.x;          // 0..511
    const int l   = tid & 63;
    const int w   = tid >> 6;             // 0..7
    const int rt  = w >> 2;               // rowtile 0/1
    const int ct  = w & 3;                // gate coltile
    const int r0  = blockIdx.x * 64;
    const int b   = r0 >> 9;
    const int n0  = r0 & (NB - 1);

    const int lane31 = l & 31;
    const int hi     = l >> 5;
    const int rA     = rt * 32 + lane31;
    const int sw0    = (lane31 & 15) << 4;
    const int jh     = ct * 32 + lane31;

    // per-lane x base (row rA, k-offset hi*8)
    const float* xlane = x + ((size_t)b * T_STEPS * NB + n0 + rA) * INDIM + hi * 8;

    // ---- issue x(0) prefetch FIRST (longest latency), then stage weights
    float4 px0, px1, px2, px3, px4, px5, px6, px7;
    {
        const float* xp = xlane;
        px0 = *(const float4*)(xp +  0); px1 = *(const float4*)(xp +  4);
        px2 = *(const float4*)(xp + 16); px3 = *(const float4*)(xp + 20);
        px4 = *(const float4*)(xp + 32); px5 = *(const float4*)(xp + 36);
        px6 = *(const float4*)(xp + 48); px7 = *(const float4*)(xp + 52);
    }
    {
        const uint4* s; uint4* d;
        s = (const uint4*)Win; d = (uint4*)WinS;
        for (int i = tid; i < 2048; i += 512) d[i] = s[i];
        s = (const uint4*)Whn; d = (uint4*)WhnS;
        for (int i = tid; i < 2048; i += 512) d[i] = s[i];
        s = (const uint4*)WmP; d = (uint4*)WmPS;
        for (int i = tid; i < 1024; i += 512) d[i] = s[i];
        uint4 z4 = make_uint4(0, 0, 0, 0);
        for (int i = tid; i < 1024; i += 512) ((uint4*)hs0)[i] = z4;
    }

    const float bRr = bc[jh], bRz = bc[128 + jh];
    const float bIN = bc[256 + jh], bHN = bc[384 + jh];
    const float bmv = bm[jh];

    const bf16_t* wrR = Wrz + (ct * 16) * 512 + l * 8;       // r coltile base
    const bf16_t* wrZ = Wrz + ((ct + 4) * 16) * 512 + l * 8; // z coltile base
    #define LDG(p) (*(const bf16x8*)(p))

    f32x16 h = {};

    for (int t = 0; t < T_STEPS; ++t) {
        const char* hsC = (t & 1) ? hs1 : hs0;
        char*       hsN = (t & 1) ? hs0 : hs1;
        BARRIER_LDS();                    // bar1: hs(t) staged; es free

        // ---- phase A: emb tile = relu(x @ Wm^T + bm) from prefetched x regs
        f32x16 accA;
        #pragma unroll
        for (int q = 0; q < 16; ++q) accA[q] = bmv;
        #define PHA(ks, VA, VB) { \
            union { bf16_t h8[8]; bf16x8 v; } pa; \
            pa.h8[0] = (bf16_t)(VA).x; pa.h8[1] = (bf16_t)(VA).y; \
            pa.h8[2] = (bf16_t)(VA).z; pa.h8[3] = (bf16_t)(VA).w; \
            pa.h8[4] = (bf16_t)(VB).x; pa.h8[5] = (bf16_t)(VB).y; \
            pa.h8[6] = (bf16_t)(VB).z; pa.h8[7] = (bf16_t)(VB).w; \
            bf16x8 bfr = *(const bf16x8*)(WmPS + (ct * 4 + (ks)) * 1024 + l * 16); \
            accA = MF(pa.v, bfr, accA); }
        PHA(0, px0, px1) PHA(1, px2, px3) PHA(2, px4, px5) PHA(3, px6, px7)
        #undef PHA
        #pragma unroll
        for (int q = 0; q < 16; ++q) {
            int rl  = (q & 3) + ((q >> 2) << 3) + (hi << 2);
            int row = rt * 32 + rl;
            *(bf16_t*)(es + row * 256 + ((jh * 2) ^ ((rl & 15) << 4))) =
                (bf16_t)fmaxf(accA[q], 0.f);
        }

        // ---- issue x(t+1) prefetch (px regs now dead)
        {
            int tn = (t + 1 < T_STEPS) ? t + 1 : T_STEPS - 1;
            const float* xp = xlane + (size_t)tn * NB * INDIM;
            px0 = *(const float4*)(xp +  0); px1 = *(const float4*)(xp +  4);
            px2 = *(const float4*)(xp + 16); px3 = *(const float4*)(xp + 20);
            px4 = *(const float4*)(xp + 32); px5 = *(const float4*)(xp + 36);
            px6 = *(const float4*)(xp + 48); px7 = *(const float4*)(xp + 52);
        }

        // ---- Wrz prefetch: 3 rotating buffers (A,B,C), issue 0..2 pre-barrier
        bf16x8 reA, rhA, zeA, zhA, reB, rhB, zeB, zhB, reC, rhC, zeC, zhC;
        #define ISSUE(BUF, k) { \
            re##BUF = LDG(wrR + (k) * 512); rh##BUF = LDG(wrR + (8 + (k)) * 512); \
            ze##BUF = LDG(wrZ + (k) * 512); zh##BUF = LDG(wrZ + (8 + (k)) * 512); }
        ISSUE(A, 0) ISSUE(B, 1) ISSUE(C, 2)

        BARRIER_LDS();                    // bar2: es ready (vmem stays in flight)

        // ---- phase B: depth-3 software pipeline over kk (3 buffers)
        f32x16 ar, az, ai, ah;
        #pragma unroll
        for (int q = 0; q < 16; ++q) { ar[q] = bRr; az[q] = bRz; ai[q] = bIN; ah[q] = bHN; }
        #define CMP(BUF, k) { \
            int off = (((k) * 2 + hi) * 16) ^ sw0; \
            bf16x8 aE = *(const bf16x8*)(es  + rA * 256 + off); \
            bf16x8 aH = *(const bf16x8*)(hsC + rA * 256 + off); \
            bf16x8 bI = *(const bf16x8*)(WinS + (ct * 8 + (k)) * 1024 + l * 16); \
            bf16x8 bN = *(const bf16x8*)(WhnS + (ct * 8 + (k)) * 1024 + l * 16); \
            ar = MF(aE, re##BUF, ar); ar = MF(aH, rh##BUF, ar); \
            az = MF(aE, ze##BUF, az); az = MF(aH, zh##BUF, az); \
            ai = MF(aE, bI, ai);      ah = MF(aH, bN, ah); }
        CMP(A, 0) ISSUE(A, 3)
        CMP(B, 1) ISSUE(B, 4)
        CMP(C, 2) ISSUE(C, 5)
        CMP(A, 3) ISSUE(A, 6)
        CMP(B, 4) ISSUE(B, 7)
        CMP(C, 5)
        CMP(A, 6)
        CMP(B, 7)
        #undef CMP
        #undef ISSUE

        // ---- phase C: lane-local gates + h update; write h(t+1) bf16 to hsN
        #pragma unroll
        for (int q = 0; q < 16; ++q) {
            int rl  = (q & 3) + ((q >> 2) << 3) + (hi << 2);
            int row = rt * 32 + rl;
            float r  = sigm_(ar[q]);
            float z  = sigm_(az[q]);
            float n  = tanh_(ai[q] + r * ah[q]);
            float hv = n + z * (h[q] - n);
            h[q] = hv;
            *(bf16_t*)(hsN + row * 256 + ((jh * 2) ^ ((rl & 15) << 4))) = (bf16_t)hv;
        }
    }

    // ---- final store (fp32) straight from registers
    #pragma unroll
    for (int q = 0; q < 16; ++q) {
        int rl = (q & 3) + ((q >> 2) << 3) + (hi << 2);
        out[(size_t)(r0 + rt * 32 + rl) * HID + jh] = h[q];
    }
    #undef LDG
}

// ---------------------------------------------------------------------------
extern "C" void kernel_launch(void* const* d_in, const int* in_sizes, int n_in,
                              void* d_out, int out_size, void* d_ws, size_t ws_size,
                              hipStream_t stream)
{
    const float* x   = (const float*)d_in[0];
    const float* Wm  = (const float*)d_in[1];
    const float* bm  = (const float*)d_in[2];
    const float* Wih = (const float*)d_in[3];
    const float* Whh = (const float*)d_in[4];
    const float* bih = (const float*)d_in[5];
    const float* bhh = (const float*)d_in[6];

    char* ws = (char*)d_ws;
    bf16_t* Wrz = (bf16_t*)(ws);                 // 131072 B
    bf16_t* Win = (bf16_t*)(ws + 131072);        //  32768 B
    bf16_t* Whn = (bf16_t*)(ws + 163840);        //  32768 B
    bf16_t* WmP = (bf16_t*)(ws + 196608);        //  16384 B
    float*  bcp = (float*) (ws + 212992);        //   2048 B

    pack_kernel<<<418, 256, 0, stream>>>(Wm, Wih, Whh, bih, bhh, Wrz, Win, Whn, WmP, bcp);
    gru_all<<<256, 512, 0, stream>>>(x, (float*)d_out, Wrz, Win, Whn, WmP, bcp, bm);
}

// Round 8
// 401.575 us; speedup vs baseline: 1.3853x; 1.3806x over previous
//
#include <hip/hip_runtime.h>
#include <hip/hip_bf16.h>

#define T_STEPS 24
#define NB      512
#define HID     128
#define INDIM   64
#define BN      16384

typedef __bf16 bf16_t;
typedef __bf16 bf16x8 __attribute__((ext_vector_type(8)));
typedef float  f32x16 __attribute__((ext_vector_type(16)));

__device__ __forceinline__ float sigm_(float x)  { return 1.f / (1.f + __expf(-x)); }
__device__ __forceinline__ float tanh_(float x)  { float e = __expf(-2.f * x); return (1.f - e) / (1.f + e); }

#define MF(a, b, c) __builtin_amdgcn_mfma_f32_32x32x16_bf16((a), (b), (c), 0, 0, 0)

// lgkmcnt-only barrier: LDS writes visible, vmem loads stay in flight.
#define BARRIER_LDS() do { \
    asm volatile("s_waitcnt lgkmcnt(0)" ::: "memory"); \
    __builtin_amdgcn_s_barrier(); \
    __builtin_amdgcn_sched_barrier(0); \
} while (0)

// ---------------------------------------------------------------------------
// Pack kernel (identical to R5, proven). Frag = [64 lanes][8 bf16] = 512 elems.
//  Wrz [8ct][16ks]: cols 0..255 = [r|z], K=256 = [emb(128)|h(128)]
//  Win [4ct][8ks]:  i_n rows of Wih (256..383), K=128 (emb)
//  Whn [4ct][8ks]:  h_n rows of Whh (256..383), K=128 (h)
//  WmP [4ct][4ks]:  W_mlp, K=64 (x)
//  bc  [512] f32:   [0..255]=bih+bhh (rz), [256..383]=bih_n, [384..511]=bhh_n
// ---------------------------------------------------------------------------
__global__ void pack_kernel(const float* __restrict__ Wm,
                            const float* __restrict__ Wih, const float* __restrict__ Whh,
                            const float* __restrict__ bih, const float* __restrict__ bhh,
                            bf16_t* __restrict__ Wrz, bf16_t* __restrict__ Win,
                            bf16_t* __restrict__ Whn, bf16_t* __restrict__ WmP,
                            float* __restrict__ bc)
{
    int tid = blockIdx.x * 256 + threadIdx.x;
    if (tid < 65536) {                         // Wrz
        int e = tid & 7, l = (tid >> 3) & 63, ks = (tid >> 9) & 15, ct = tid >> 13;
        int col = ct * 32 + (l & 31);
        int k   = ks * 16 + ((l >> 5) << 3) + e;
        float v = (k < 128) ? Wih[col * HID + k] : Whh[col * HID + (k - 128)];
        Wrz[tid] = (bf16_t)v;
    } else if (tid < 81920) {                  // Win
        int u = tid - 65536;
        int e = u & 7, l = (u >> 3) & 63, ks = (u >> 9) & 7, ct = u >> 12;
        int col = ct * 32 + (l & 31);
        int k   = ks * 16 + ((l >> 5) << 3) + e;
        Win[u] = (bf16_t)Wih[(256 + col) * HID + k];
    } else if (tid < 98304) {                  // Whn
        int u = tid - 81920;
        int e = u & 7, l = (u >> 3) & 63, ks = (u >> 9) & 7, ct = u >> 12;
        int col = ct * 32 + (l & 31);
        int k   = ks * 16 + ((l >> 5) << 3) + e;
        Whn[u] = (bf16_t)Whh[(256 + col) * HID + k];
    } else if (tid < 106496) {                 // WmP
        int u = tid - 98304;
        int e = u & 7, l = (u >> 3) & 63, ks = (u >> 9) & 3, ct = u >> 11;
        int col = ct * 32 + (l & 31);
        int k   = ks * 16 + ((l >> 5) << 3) + e;
        WmP[u] = (bf16_t)Wm[col * INDIM + k];
    } else if (tid < 107008) {                 // bc
        int j = tid - 106496;
        float v;
        if (j < 256)      v = bih[j] + bhh[j];
        else if (j < 384) v = bih[j];
        else              v = bhh[j - 128];
        bc[j] = v;
    }
}

// ---------------------------------------------------------------------------
// Persistent GRU: 256 blocks x 512 threads (8 waves, 2/SIMD), 64 rows/block.
// amdgpu_waves_per_eu(2,2): LDS (128K) caps occupancy at 8 waves/CU = 2/EU
// anyway, so pin the allocator's budget at 512/2 = 256 VGPRs (launch_bounds'
// 2nd arg was NOT honored in R5-R7: VGPR stuck at 128 -> loop-carried spills,
// 476 MB of scratch reloads). t-loop explicitly not unrolled.
// ---------------------------------------------------------------------------
__global__ __launch_bounds__(512)
__attribute__((amdgpu_waves_per_eu(2, 2)))
void gru_all(
    const float*  __restrict__ x, float* __restrict__ out,
    const bf16_t* __restrict__ Wrz, const bf16_t* __restrict__ Win,
    const bf16_t* __restrict__ Whn, const bf16_t* __restrict__ WmP,
    const float*  __restrict__ bc,  const float* __restrict__ bm)
{
    __shared__ __align__(16) char WinS[32768];
    __shared__ __align__(16) char WhnS[32768];
    __shared__ __align__(16) char WmPS[16384];
    __shared__ __align__(16) char es  [16384];
    __shared__ __align__(16) char hs0 [16384], hs1[16384];

    const int tid = threadIdx.x;          // 0..511
    const int l   = tid & 63;
    const int w   = tid >> 6;             // 0..7
    const int rt  = w >> 2;               // rowtile 0/1
    const int ct  = w & 3;                // gate coltile
    const int r0  = blockIdx.x * 64;
    const int b   = r0 >> 9;
    const int n0  = r0 & (NB - 1);

    const int lane31 = l & 31;
    const int hi     = l >> 5;
    const int rA     = rt * 32 + lane31;
    const int sw0    = (lane31 & 15) << 4;
    const int jh     = ct * 32 + lane31;

    // per-lane x base (row rA, k-offset hi*8)
    const float* xlane = x + ((size_t)b * T_STEPS * NB + n0 + rA) * INDIM + hi * 8;

    // ---- stage step-invariant weight caches; zero hs0 (h(0)=0)
    {
        const uint4* s; uint4* d;
        s = (const uint4*)Win; d = (uint4*)WinS;
        for (int i = tid; i < 2048; i += 512) d[i] = s[i];
        s = (const uint4*)Whn; d = (uint4*)WhnS;
        for (int i = tid; i < 2048; i += 512) d[i] = s[i];
        s = (const uint4*)WmP; d = (uint4*)WmPS;
        for (int i = tid; i < 1024; i += 512) d[i] = s[i];
        uint4 z4 = make_uint4(0, 0, 0, 0);
        for (int i = tid; i < 1024; i += 512) ((uint4*)hs0)[i] = z4;
    }

    const float bRr = bc[jh], bRz = bc[128 + jh];
    const float bIN = bc[256 + jh], bHN = bc[384 + jh];
    const float bmv = bm[jh];

    const bf16_t* wrR = Wrz + (ct * 16) * 512 + l * 8;       // r coltile base
    const bf16_t* wrZ = Wrz + ((ct + 4) * 16) * 512 + l * 8; // z coltile base
    #define LDG(p) (*(const bf16x8*)(p))

    f32x16 h = {};

    #pragma unroll 1
    for (int t = 0; t < T_STEPS; ++t) {
        const char* hsC = (t & 1) ? hs1 : hs0;
        char*       hsN = (t & 1) ? hs0 : hs1;
        BARRIER_LDS();                    // bar1: hs(t) staged; es free

        // ---- phase A: emb tile = relu(x @ Wm^T + bm); x direct from global
        const float* xt = xlane + (size_t)t * NB * INDIM;
        float4 xv0 = *(const float4*)(xt +  0), xv1 = *(const float4*)(xt +  4);
        float4 xv2 = *(const float4*)(xt + 16), xv3 = *(const float4*)(xt + 20);
        float4 xv4 = *(const float4*)(xt + 32), xv5 = *(const float4*)(xt + 36);
        float4 xv6 = *(const float4*)(xt + 48), xv7 = *(const float4*)(xt + 52);
        f32x16 accA;
        #pragma unroll
        for (int q = 0; q < 16; ++q) accA[q] = bmv;
        #define PHA(ks, VA, VB) { \
            union { bf16_t h8[8]; bf16x8 v; } pa; \
            pa.h8[0] = (bf16_t)(VA).x; pa.h8[1] = (bf16_t)(VA).y; \
            pa.h8[2] = (bf16_t)(VA).z; pa.h8[3] = (bf16_t)(VA).w; \
            pa.h8[4] = (bf16_t)(VB).x; pa.h8[5] = (bf16_t)(VB).y; \
            pa.h8[6] = (bf16_t)(VB).z; pa.h8[7] = (bf16_t)(VB).w; \
            bf16x8 bfr = *(const bf16x8*)(WmPS + (ct * 4 + (ks)) * 1024 + l * 16); \
            accA = MF(pa.v, bfr, accA); }
        PHA(0, xv0, xv1) PHA(1, xv2, xv3) PHA(2, xv4, xv5) PHA(3, xv6, xv7)
        #undef PHA
        #pragma unroll
        for (int q = 0; q < 16; ++q) {
            int rl  = (q & 3) + ((q >> 2) << 3) + (hi << 2);
            int row = rt * 32 + rl;
            *(bf16_t*)(es + row * 256 + ((jh * 2) ^ ((rl & 15) << 4))) =
                (bf16_t)fmaxf(accA[q], 0.f);
        }

        // ---- Wrz prefetch: 3 rotating buffers (A,B,C), issue 0..2 pre-barrier
        bf16x8 reA, rhA, zeA, zhA, reB, rhB, zeB, zhB, reC, rhC, zeC, zhC;
        #define ISSUE(BUF, k) { \
            re##BUF = LDG(wrR + (k) * 512); rh##BUF = LDG(wrR + (8 + (k)) * 512); \
            ze##BUF = LDG(wrZ + (k) * 512); zh##BUF = LDG(wrZ + (8 + (k)) * 512); }
        ISSUE(A, 0) ISSUE(B, 1) ISSUE(C, 2)

        BARRIER_LDS();                    // bar2: es ready (vmem stays in flight)

        // ---- phase B: depth-3 software pipeline over kk (3 buffers)
        f32x16 ar, az, ai, ah;
        #pragma unroll
        for (int q = 0; q < 16; ++q) { ar[q] = bRr; az[q] = bRz; ai[q] = bIN; ah[q] = bHN; }
        #define CMP(BUF, k) { \
            int off = (((k) * 2 + hi) * 16) ^ sw0; \
            bf16x8 aE = *(const bf16x8*)(es  + rA * 256 + off); \
            bf16x8 aH = *(const bf16x8*)(hsC + rA * 256 + off); \
            bf16x8 bI = *(const bf16x8*)(WinS + (ct * 8 + (k)) * 1024 + l * 16); \
            bf16x8 bN = *(const bf16x8*)(WhnS + (ct * 8 + (k)) * 1024 + l * 16); \
            ar = MF(aE, re##BUF, ar); ar = MF(aH, rh##BUF, ar); \
            az = MF(aE, ze##BUF, az); az = MF(aH, zh##BUF, az); \
            ai = MF(aE, bI, ai);      ah = MF(aH, bN, ah); }
        CMP(A, 0) ISSUE(A, 3)
        CMP(B, 1) ISSUE(B, 4)
        CMP(C, 2) ISSUE(C, 5)
        CMP(A, 3) ISSUE(A, 6)
        CMP(B, 4) ISSUE(B, 7)
        CMP(C, 5)
        CMP(A, 6)
        CMP(B, 7)
        #undef CMP
        #undef ISSUE

        // ---- phase C: lane-local gates + h update; write h(t+1) bf16 to hsN
        #pragma unroll
        for (int q = 0; q < 16; ++q) {
            int rl  = (q & 3) + ((q >> 2) << 3) + (hi << 2);
            int row = rt * 32 + rl;
            float r  = sigm_(ar[q]);
            float z  = sigm_(az[q]);
            float n  = tanh_(ai[q] + r * ah[q]);
            float hv = n + z * (h[q] - n);
            h[q] = hv;
            *(bf16_t*)(hsN + row * 256 + ((jh * 2) ^ ((rl & 15) << 4))) = (bf16_t)hv;
        }
    }

    // ---- final store (fp32) straight from registers
    #pragma unroll
    for (int q = 0; q < 16; ++q) {
        int rl = (q & 3) + ((q >> 2) << 3) + (hi << 2);
        out[(size_t)(r0 + rt * 32 + rl) * HID + jh] = h[q];
    }
    #undef LDG
}

// ---------------------------------------------------------------------------
extern "C" void kernel_launch(void* const* d_in, const int* in_sizes, int n_in,
                              void* d_out, int out_size, void* d_ws, size_t ws_size,
                              hipStream_t stream)
{
    const float* x   = (const float*)d_in[0];
    const float* Wm  = (const float*)d_in[1];
    const float* bm  = (const float*)d_in[2];
    const float* Wih = (const float*)d_in[3];
    const float* Whh = (const float*)d_in[4];
    const float* bih = (const float*)d_in[5];
    const float* bhh = (const float*)d_in[6];

    char* ws = (char*)d_ws;
    bf16_t* Wrz = (bf16_t*)(ws);                 // 131072 B
    bf16_t* Win = (bf16_t*)(ws + 131072);        //  32768 B
    bf16_t* Whn = (bf16_t*)(ws + 163840);        //  32768 B
    bf16_t* WmP = (bf16_t*)(ws + 196608);        //  16384 B
    float*  bcp = (float*) (ws + 212992);        //   2048 B

    pack_kernel<<<418, 256, 0, stream>>>(Wm, Wih, Whh, bih, bhh, Wrz, Win, Whn, WmP, bcp);
    gru_all<<<256, 512, 0, stream>>>(x, (float*)d_out, Wrz, Win, Whn, WmP, bcp, bm);
}

// Round 9
// 192.821 us; speedup vs baseline: 2.8851x; 2.0826x over previous
//
#include <hip/hip_runtime.h>
#include <hip/hip_bf16.h>

#define T_STEPS 24
#define NB      512
#define HID     128
#define INDIM   64
#define BN      16384

typedef __bf16 bf16_t;
typedef __bf16 bf16x8 __attribute__((ext_vector_type(8)));
typedef float  f32x16 __attribute__((ext_vector_type(16)));

__device__ __forceinline__ float sigm_(float x)  { return 1.f / (1.f + __expf(-x)); }
__device__ __forceinline__ float tanh_(float x)  { float e = __expf(-2.f * x); return (1.f - e) / (1.f + e); }

#define MF(a, b, c) __builtin_amdgcn_mfma_f32_32x32x16_bf16((a), (b), (c), 0, 0, 0)

// lgkmcnt-only barrier: LDS writes visible, vmem loads stay in flight.
#define BARRIER_LDS() do { \
    asm volatile("s_waitcnt lgkmcnt(0)" ::: "memory"); \
    __builtin_amdgcn_s_barrier(); \
    __builtin_amdgcn_sched_barrier(0); \
} while (0)

// ---------------------------------------------------------------------------
// Pack kernel (identical since R5, proven). Frag = [64 lanes][8 bf16] = 512 el.
//  Wrz [8ct][16ks]: cols 0..255 = [r|z], K=256 = [emb(128)|h(128)]
//  Win [4ct][8ks]:  i_n rows of Wih (256..383), K=128 (emb)
//  Whn [4ct][8ks]:  h_n rows of Whh (256..383), K=128 (h)
//  WmP [4ct][4ks]:  W_mlp, K=64 (x)
//  bc  [512] f32:   [0..255]=bih+bhh (rz), [256..383]=bih_n, [384..511]=bhh_n
// ---------------------------------------------------------------------------
__global__ void pack_kernel(const float* __restrict__ Wm,
                            const float* __restrict__ Wih, const float* __restrict__ Whh,
                            const float* __restrict__ bih, const float* __restrict__ bhh,
                            bf16_t* __restrict__ Wrz, bf16_t* __restrict__ Win,
                            bf16_t* __restrict__ Whn, bf16_t* __restrict__ WmP,
                            float* __restrict__ bc)
{
    int tid = blockIdx.x * 256 + threadIdx.x;
    if (tid < 65536) {                         // Wrz
        int e = tid & 7, l = (tid >> 3) & 63, ks = (tid >> 9) & 15, ct = tid >> 13;
        int col = ct * 32 + (l & 31);
        int k   = ks * 16 + ((l >> 5) << 3) + e;
        float v = (k < 128) ? Wih[col * HID + k] : Whh[col * HID + (k - 128)];
        Wrz[tid] = (bf16_t)v;
    } else if (tid < 81920) {                  // Win
        int u = tid - 65536;
        int e = u & 7, l = (u >> 3) & 63, ks = (u >> 9) & 7, ct = u >> 12;
        int col = ct * 32 + (l & 31);
        int k   = ks * 16 + ((l >> 5) << 3) + e;
        Win[u] = (bf16_t)Wih[(256 + col) * HID + k];
    } else if (tid < 98304) {                  // Whn
        int u = tid - 81920;
        int e = u & 7, l = (u >> 3) & 63, ks = (u >> 9) & 7, ct = u >> 12;
        int col = ct * 32 + (l & 31);
        int k   = ks * 16 + ((l >> 5) << 3) + e;
        Whn[u] = (bf16_t)Whh[(256 + col) * HID + k];
    } else if (tid < 106496) {                 // WmP
        int u = tid - 98304;
        int e = u & 7, l = (u >> 3) & 63, ks = (u >> 9) & 3, ct = u >> 11;
        int col = ct * 32 + (l & 31);
        int k   = ks * 16 + ((l >> 5) << 3) + e;
        WmP[u] = (bf16_t)Wm[col * INDIM + k];
    } else if (tid < 107008) {                 // bc
        int j = tid - 106496;
        float v;
        if (j < 256)      v = bih[j] + bhh[j];
        else if (j < 384) v = bih[j];
        else              v = bhh[j - 128];
        bc[j] = v;
    }
}

// ---------------------------------------------------------------------------
// Persistent GRU: 256 blocks x 512 threads (8 waves, 2/SIMD), 64 rows/block.
// R9: LOW ARCH-VGPR PRESSURE version. The backend pins arch VGPRs at 128 for
// this kernel regardless of launch_bounds/waves_per_eu (R5-R8 evidence), so
// the named Wrz register-prefetch (48 VGPRs) is removed: phase B loads Wrz
// directly, unroll-2, compiler-scheduled. Demand ~90 arch regs < 128.
// ---------------------------------------------------------------------------
__global__ __launch_bounds__(512)
__attribute__((amdgpu_waves_per_eu(2, 2)))
void gru_all(
    const float*  __restrict__ x, float* __restrict__ out,
    const bf16_t* __restrict__ Wrz, const bf16_t* __restrict__ Win,
    const bf16_t* __restrict__ Whn, const bf16_t* __restrict__ WmP,
    const float*  __restrict__ bc,  const float* __restrict__ bm)
{
    __shared__ __align__(16) char WinS[32768];
    __shared__ __align__(16) char WhnS[32768];
    __shared__ __align__(16) char WmPS[16384];
    __shared__ __align__(16) char es  [16384];
    __shared__ __align__(16) char hs0 [16384], hs1[16384];

    const int tid = threadIdx.x;          // 0..511
    const int l   = tid & 63;
    const int w   = tid >> 6;             // 0..7
    const int rt  = w >> 2;               // rowtile 0/1
    const int ct  = w & 3;                // gate coltile
    const int r0  = blockIdx.x * 64;
    const int b   = r0 >> 9;
    const int n0  = r0 & (NB - 1);

    const int lane31 = l & 31;
    const int hi     = l >> 5;
    const int rA     = rt * 32 + lane31;
    const int sw0    = (lane31 & 15) << 4;
    const int jh     = ct * 32 + lane31;

    // per-lane x base (row rA, k-offset hi*8)
    const float* xlane = x + ((size_t)b * T_STEPS * NB + n0 + rA) * INDIM + hi * 8;

    // ---- stage step-invariant weight caches; zero hs0 (h(0)=0)
    {
        const uint4* s; uint4* d;
        s = (const uint4*)Win; d = (uint4*)WinS;
        for (int i = tid; i < 2048; i += 512) d[i] = s[i];
        s = (const uint4*)Whn; d = (uint4*)WhnS;
        for (int i = tid; i < 2048; i += 512) d[i] = s[i];
        s = (const uint4*)WmP; d = (uint4*)WmPS;
        for (int i = tid; i < 1024; i += 512) d[i] = s[i];
        uint4 z4 = make_uint4(0, 0, 0, 0);
        for (int i = tid; i < 1024; i += 512) ((uint4*)hs0)[i] = z4;
    }

    const float bRr = bc[jh], bRz = bc[128 + jh];
    const float bIN = bc[256 + jh], bHN = bc[384 + jh];
    const float bmv = bm[jh];

    const bf16_t* wrR = Wrz + (ct * 16) * 512 + l * 8;       // r coltile base
    const bf16_t* wrZ = Wrz + ((ct + 4) * 16) * 512 + l * 8; // z coltile base
    #define LDG(p) (*(const bf16x8*)(p))

    f32x16 h = {};

    #pragma unroll 1
    for (int t = 0; t < T_STEPS; ++t) {
        const char* hsC = (t & 1) ? hs1 : hs0;
        char*       hsN = (t & 1) ? hs0 : hs1;
        BARRIER_LDS();                    // bar1: hs(t) staged; es free

        // ---- phase A: emb tile = relu(x @ Wm^T + bm); x direct from global
        const float* xt = xlane + (size_t)t * NB * INDIM;
        float4 xv0 = *(const float4*)(xt +  0), xv1 = *(const float4*)(xt +  4);
        float4 xv2 = *(const float4*)(xt + 16), xv3 = *(const float4*)(xt + 20);
        float4 xv4 = *(const float4*)(xt + 32), xv5 = *(const float4*)(xt + 36);
        float4 xv6 = *(const float4*)(xt + 48), xv7 = *(const float4*)(xt + 52);
        f32x16 accA;
        #pragma unroll
        for (int q = 0; q < 16; ++q) accA[q] = bmv;
        #define PHA(ks, VA, VB) { \
            union { bf16_t h8[8]; bf16x8 v; } pa; \
            pa.h8[0] = (bf16_t)(VA).x; pa.h8[1] = (bf16_t)(VA).y; \
            pa.h8[2] = (bf16_t)(VA).z; pa.h8[3] = (bf16_t)(VA).w; \
            pa.h8[4] = (bf16_t)(VB).x; pa.h8[5] = (bf16_t)(VB).y; \
            pa.h8[6] = (bf16_t)(VB).z; pa.h8[7] = (bf16_t)(VB).w; \
            bf16x8 bfr = *(const bf16x8*)(WmPS + (ct * 4 + (ks)) * 1024 + l * 16); \
            accA = MF(pa.v, bfr, accA); }
        PHA(0, xv0, xv1) PHA(1, xv2, xv3) PHA(2, xv4, xv5) PHA(3, xv6, xv7)
        #undef PHA
        #pragma unroll
        for (int q = 0; q < 16; ++q) {
            int rl  = (q & 3) + ((q >> 2) << 3) + (hi << 2);
            int row = rt * 32 + rl;
            *(bf16_t*)(es + row * 256 + ((jh * 2) ^ ((rl & 15) << 4))) =
                (bf16_t)fmaxf(accA[q], 0.f);
        }

        BARRIER_LDS();                    // bar2: es ready

        // ---- phase B: direct loads, compiler-scheduled (low reg pressure)
        f32x16 ar, az, ai, ah;
        #pragma unroll
        for (int q = 0; q < 16; ++q) { ar[q] = bRr; az[q] = bRz; ai[q] = bIN; ah[q] = bHN; }
        #pragma unroll 2
        for (int kk = 0; kk < 8; ++kk) {
            int off = ((kk * 2 + hi) * 16) ^ sw0;
            bf16x8 aE  = *(const bf16x8*)(es  + rA * 256 + off);
            bf16x8 aH  = *(const bf16x8*)(hsC + rA * 256 + off);
            bf16x8 bRe = LDG(wrR + kk * 512);
            bf16x8 bRh = LDG(wrR + (8 + kk) * 512);
            bf16x8 bZe = LDG(wrZ + kk * 512);
            bf16x8 bZh = LDG(wrZ + (8 + kk) * 512);
            bf16x8 bI  = *(const bf16x8*)(WinS + (ct * 8 + kk) * 1024 + l * 16);
            bf16x8 bN  = *(const bf16x8*)(WhnS + (ct * 8 + kk) * 1024 + l * 16);
            ar = MF(aE, bRe, ar); ar = MF(aH, bRh, ar);
            az = MF(aE, bZe, az); az = MF(aH, bZh, az);
            ai = MF(aE, bI,  ai); ah = MF(aH, bN,  ah);
        }

        // ---- phase C: lane-local gates + h update; write h(t+1) bf16 to hsN
        #pragma unroll
        for (int q = 0; q < 16; ++q) {
            int rl  = (q & 3) + ((q >> 2) << 3) + (hi << 2);
            int row = rt * 32 + rl;
            float r  = sigm_(ar[q]);
            float z  = sigm_(az[q]);
            float n  = tanh_(ai[q] + r * ah[q]);
            float hv = n + z * (h[q] - n);
            h[q] = hv;
            *(bf16_t*)(hsN + row * 256 + ((jh * 2) ^ ((rl & 15) << 4))) = (bf16_t)hv;
        }
    }

    // ---- final store (fp32) straight from registers
    #pragma unroll
    for (int q = 0; q < 16; ++q) {
        int rl = (q & 3) + ((q >> 2) << 3) + (hi << 2);
        out[(size_t)(r0 + rt * 32 + rl) * HID + jh] = h[q];
    }
    #undef LDG
}

// ---------------------------------------------------------------------------
extern "C" void kernel_launch(void* const* d_in, const int* in_sizes, int n_in,
                              void* d_out, int out_size, void* d_ws, size_t ws_size,
                              hipStream_t stream)
{
    const float* x   = (const float*)d_in[0];
    const float* Wm  = (const float*)d_in[1];
    const float* bm  = (const float*)d_in[2];
    const float* Wih = (const float*)d_in[3];
    const float* Whh = (const float*)d_in[4];
    const float* bih = (const float*)d_in[5];
    const float* bhh = (const float*)d_in[6];

    char* ws = (char*)d_ws;
    bf16_t* Wrz = (bf16_t*)(ws);                 // 131072 B
    bf16_t* Win = (bf16_t*)(ws + 131072);        //  32768 B
    bf16_t* Whn = (bf16_t*)(ws + 163840);        //  32768 B
    bf16_t* WmP = (bf16_t*)(ws + 196608);        //  16384 B
    float*  bcp = (float*) (ws + 212992);        //   2048 B

    pack_kernel<<<418, 256, 0, stream>>>(Wm, Wih, Whh, bih, bhh, Wrz, Win, Whn, WmP, bcp);
    gru_all<<<256, 512, 0, stream>>>(x, (float*)d_out, Wrz, Win, Whn, WmP, bcp, bm);
}

// Round 10
// 129.282 us; speedup vs baseline: 4.3031x; 1.4915x over previous
//
#include <hip/hip_runtime.h>
#include <hip/hip_bf16.h>

#define T_STEPS 24
#define NB      512
#define HID     128
#define INDIM   64
#define BN      16384

typedef __bf16 bf16_t;
typedef __bf16 bf16x8 __attribute__((ext_vector_type(8)));
typedef float  f32x16 __attribute__((ext_vector_type(16)));

__device__ __forceinline__ float rcp_(float x) { return __builtin_amdgcn_rcpf(x); }
__device__ __forceinline__ float sigm_(float x) { return rcp_(1.f + __expf(-x)); }
__device__ __forceinline__ float tanh_(float x) { float e = __expf(-2.f * x); return (1.f - e) * rcp_(1.f + e); }

#define MF(a, b, c) __builtin_amdgcn_mfma_f32_32x32x16_bf16((a), (b), (c), 0, 0, 0)

// bar1: full drain — x-DMA (vmcnt) complete + LDS visible.
#define BARRIER_FULL() do { \
    asm volatile("s_waitcnt vmcnt(0) lgkmcnt(0)" ::: "memory"); \
    __builtin_amdgcn_s_barrier(); \
    __builtin_amdgcn_sched_barrier(0); \
} while (0)
// bar2: lgkmcnt-only — vmem loads stay in flight.
#define BARRIER_LDS() do { \
    asm volatile("s_waitcnt lgkmcnt(0)" ::: "memory"); \
    __builtin_amdgcn_s_barrier(); \
    __builtin_amdgcn_sched_barrier(0); \
} while (0)

typedef const __attribute__((address_space(1))) unsigned int* gp1_t;
typedef __attribute__((address_space(3))) unsigned int* lp3_t;
#define GLOAD_LDS16(g, l) __builtin_amdgcn_global_load_lds((gp1_t)(g), (lp3_t)(l), 16, 0, 0)

// ---------------------------------------------------------------------------
// Pack kernel (identical since R5, proven). Frag = [64 lanes][8 bf16] = 512 el.
//  Wrz [8ct][16ks]: cols 0..255 = [r|z], K=256 = [emb(128)|h(128)]
//  Win [4ct][8ks]:  i_n rows of Wih (256..383), K=128 (emb)
//  Whn [4ct][8ks]:  h_n rows of Whh (256..383), K=128 (h)
//  WmP [4ct][4ks]:  W_mlp, K=64 (x)
//  bc  [512] f32:   [0..255]=bih+bhh (rz), [256..383]=bih_n, [384..511]=bhh_n
// ---------------------------------------------------------------------------
__global__ void pack_kernel(const float* __restrict__ Wm,
                            const float* __restrict__ Wih, const float* __restrict__ Whh,
                            const float* __restrict__ bih, const float* __restrict__ bhh,
                            bf16_t* __restrict__ Wrz, bf16_t* __restrict__ Win,
                            bf16_t* __restrict__ Whn, bf16_t* __restrict__ WmP,
                            float* __restrict__ bc)
{
    int tid = blockIdx.x * 256 + threadIdx.x;
    if (tid < 65536) {                         // Wrz
        int e = tid & 7, l = (tid >> 3) & 63, ks = (tid >> 9) & 15, ct = tid >> 13;
        int col = ct * 32 + (l & 31);
        int k   = ks * 16 + ((l >> 5) << 3) + e;
        float v = (k < 128) ? Wih[col * HID + k] : Whh[col * HID + (k - 128)];
        Wrz[tid] = (bf16_t)v;
    } else if (tid < 81920) {                  // Win
        int u = tid - 65536;
        int e = u & 7, l = (u >> 3) & 63, ks = (u >> 9) & 7, ct = u >> 12;
        int col = ct * 32 + (l & 31);
        int k   = ks * 16 + ((l >> 5) << 3) + e;
        Win[u] = (bf16_t)Wih[(256 + col) * HID + k];
    } else if (tid < 98304) {                  // Whn
        int u = tid - 81920;
        int e = u & 7, l = (u >> 3) & 63, ks = (u >> 9) & 7, ct = u >> 12;
        int col = ct * 32 + (l & 31);
        int k   = ks * 16 + ((l >> 5) << 3) + e;
        Whn[u] = (bf16_t)Whh[(256 + col) * HID + k];
    } else if (tid < 106496) {                 // WmP
        int u = tid - 98304;
        int e = u & 7, l = (u >> 3) & 63, ks = (u >> 9) & 3, ct = u >> 11;
        int col = ct * 32 + (l & 31);
        int k   = ks * 16 + ((l >> 5) << 3) + e;
        WmP[u] = (bf16_t)Wm[col * INDIM + k];
    } else if (tid < 107008) {                 // bc
        int j = tid - 106496;
        float v;
        if (j < 256)      v = bih[j] + bhh[j];
        else if (j < 384) v = bih[j];
        else              v = bhh[j - 128];
        bc[j] = v;
    }
}

// ---------------------------------------------------------------------------
// Persistent GRU: 256 blocks x 512 threads (8 waves, 2/SIMD), 64 rows/block.
// R10 = R9 + (a) rcp-based gates (kills IEEE div sequences),
//            (b) x staged in LDS via global_load_lds, issued at bar2 of step
//                t-1 -> HBM/L3 latency hidden under phase B+C.
// xs: [64 rows][16 slots of 16B] fp32, slot s of row r holds x cols
// 4*(s^(r&15)).. (source pre-swizzle; LDS dest linear per m104/m173).
// LDS total 144 KiB -> 1 block/CU.
// ---------------------------------------------------------------------------
__global__ __launch_bounds__(512)
__attribute__((amdgpu_waves_per_eu(2, 2)))
void gru_all(
    const float*  __restrict__ x, float* __restrict__ out,
    const bf16_t* __restrict__ Wrz, const bf16_t* __restrict__ Win,
    const bf16_t* __restrict__ Whn, const bf16_t* __restrict__ WmP,
    const float*  __restrict__ bc,  const float* __restrict__ bm)
{
    __shared__ __align__(16) char WinS[32768];
    __shared__ __align__(16) char WhnS[32768];
    __shared__ __align__(16) char WmPS[16384];
    __shared__ __align__(16) char es  [16384];
    __shared__ __align__(16) char hs0 [16384], hs1[16384];
    __shared__ __align__(16) char xs  [16384];   // 64 x 64 fp32, swizzled

    const int tid = threadIdx.x;          // 0..511
    const int l   = tid & 63;
    const int w   = tid >> 6;             // 0..7
    const int rt  = w >> 2;               // rowtile 0/1
    const int ct  = w & 3;                // gate coltile
    const int r0  = blockIdx.x * 64;
    const int b   = r0 >> 9;
    const int n0  = r0 & (NB - 1);

    const int lane31 = l & 31;
    const int hi     = l >> 5;
    const int rA     = rt * 32 + lane31;
    const int sw0    = (lane31 & 15) << 4;
    const int jh     = ct * 32 + lane31;

    // ---- x-DMA per-lane source offsets (bytes) + wave-uniform LDS dests
    const int rowD0 = w * 8 + (l >> 4);          // instruction 0 row
    const int rowD1 = rowD0 + 4;                 // instruction 1 row
    const int oD0   = rowD0 * 256 + ((((l & 15) ^ (rowD0 & 15))) << 4);
    const int oD1   = rowD1 * 256 + ((((l & 15) ^ (rowD1 & 15))) << 4);
    const char* xb0 = (const char*)(x + ((size_t)b * T_STEPS * NB + n0) * INDIM);
    char* ldst = xs + w * 2048;

    // ---- stage x(0) DMA first (longest latency)
    GLOAD_LDS16(xb0 + oD0, ldst);
    GLOAD_LDS16(xb0 + oD1, ldst + 1024);

    // ---- stage step-invariant weight caches; zero hs0 (h(0)=0)
    {
        const uint4* s; uint4* d;
        s = (const uint4*)Win; d = (uint4*)WinS;
        for (int i = tid; i < 2048; i += 512) d[i] = s[i];
        s = (const uint4*)Whn; d = (uint4*)WhnS;
        for (int i = tid; i < 2048; i += 512) d[i] = s[i];
        s = (const uint4*)WmP; d = (uint4*)WmPS;
        for (int i = tid; i < 1024; i += 512) d[i] = s[i];
        uint4 z4 = make_uint4(0, 0, 0, 0);
        for (int i = tid; i < 1024; i += 512) ((uint4*)hs0)[i] = z4;
    }

    const float bRr = bc[jh], bRz = bc[128 + jh];
    const float bIN = bc[256 + jh], bHN = bc[384 + jh];
    const float bmv = bm[jh];

    const bf16_t* wrR = Wrz + (ct * 16) * 512 + l * 8;       // r coltile base
    const bf16_t* wrZ = Wrz + ((ct + 4) * 16) * 512 + l * 8; // z coltile base
    #define LDG(p) (*(const bf16x8*)(p))

    f32x16 h = {};

    #pragma unroll 1
    for (int t = 0; t < T_STEPS; ++t) {
        const char* hsC = (t & 1) ? hs1 : hs0;
        char*       hsN = (t & 1) ? hs0 : hs1;
        BARRIER_FULL();                   // x(t) DMA complete; hs(t) visible

        // ---- phase A: emb tile = relu(x @ Wm^T + bm); x from swizzled LDS
        f32x16 accA;
        #pragma unroll
        for (int q = 0; q < 16; ++q) accA[q] = bmv;
        const int sAr = rA * 256;
        #define PHA(ks) { \
            int g0 = ((ks) * 4 + hi * 2) * 16; \
            float4 fa = *(const float4*)(xs + sAr + (g0 ^ sw0)); \
            float4 fb = *(const float4*)(xs + sAr + ((g0 + 16) ^ sw0)); \
            union { bf16_t h8[8]; bf16x8 v; } pa; \
            pa.h8[0] = (bf16_t)fa.x; pa.h8[1] = (bf16_t)fa.y; \
            pa.h8[2] = (bf16_t)fa.z; pa.h8[3] = (bf16_t)fa.w; \
            pa.h8[4] = (bf16_t)fb.x; pa.h8[5] = (bf16_t)fb.y; \
            pa.h8[6] = (bf16_t)fb.z; pa.h8[7] = (bf16_t)fb.w; \
            bf16x8 bfr = *(const bf16x8*)(WmPS + (ct * 4 + (ks)) * 1024 + l * 16); \
            accA = MF(pa.v, bfr, accA); }
        PHA(0) PHA(1) PHA(2) PHA(3)
        #undef PHA
        #pragma unroll
        for (int q = 0; q < 16; ++q) {
            int rl  = (q & 3) + ((q >> 2) << 3) + (hi << 2);
            int row = rt * 32 + rl;
            *(bf16_t*)(es + row * 256 + ((jh * 2) ^ ((rl & 15) << 4))) =
                (bf16_t)fmaxf(accA[q], 0.f);
        }

        BARRIER_LDS();                    // es ready; all xs reads drained

        // ---- issue x(t+1) DMA (overwrites xs; safe after bar2)
        if (t + 1 < T_STEPS) {
            const char* xbn = xb0 + (size_t)(t + 1) * NB * INDIM * 4;
            GLOAD_LDS16(xbn + oD0, ldst);
            GLOAD_LDS16(xbn + oD1, ldst + 1024);
        }

        // ---- phase B: direct loads, compiler-scheduled (low reg pressure)
        f32x16 ar, az, ai, ah;
        #pragma unroll
        for (int q = 0; q < 16; ++q) { ar[q] = bRr; az[q] = bRz; ai[q] = bIN; ah[q] = bHN; }
        #pragma unroll 2
        for (int kk = 0; kk < 8; ++kk) {
            int off = ((kk * 2 + hi) * 16) ^ sw0;
            bf16x8 aE  = *(const bf16x8*)(es  + rA * 256 + off);
            bf16x8 aH  = *(const bf16x8*)(hsC + rA * 256 + off);
            bf16x8 bRe = LDG(wrR + kk * 512);
            bf16x8 bRh = LDG(wrR + (8 + kk) * 512);
            bf16x8 bZe = LDG(wrZ + kk * 512);
            bf16x8 bZh = LDG(wrZ + (8 + kk) * 512);
            bf16x8 bI  = *(const bf16x8*)(WinS + (ct * 8 + kk) * 1024 + l * 16);
            bf16x8 bN  = *(const bf16x8*)(WhnS + (ct * 8 + kk) * 1024 + l * 16);
            ar = MF(aE, bRe, ar); ar = MF(aH, bRh, ar);
            az = MF(aE, bZe, az); az = MF(aH, bZh, az);
            ai = MF(aE, bI,  ai); ah = MF(aH, bN,  ah);
        }

        // ---- phase C: lane-local gates (rcp-based) + h update -> hsN (bf16)
        #pragma unroll
        for (int q = 0; q < 16; ++q) {
            int rl  = (q & 3) + ((q >> 2) << 3) + (hi << 2);
            int row = rt * 32 + rl;
            float r  = sigm_(ar[q]);
            float z  = sigm_(az[q]);
            float n  = tanh_(ai[q] + r * ah[q]);
            float hv = n + z * (h[q] - n);
            h[q] = hv;
            *(bf16_t*)(hsN + row * 256 + ((jh * 2) ^ ((rl & 15) << 4))) = (bf16_t)hv;
        }
    }

    // ---- final store (fp32) straight from registers
    #pragma unroll
    for (int q = 0; q < 16; ++q) {
        int rl = (q & 3) + ((q >> 2) << 3) + (hi << 2);
        out[(size_t)(r0 + rt * 32 + rl) * HID + jh] = h[q];
    }
    #undef LDG
}

// ---------------------------------------------------------------------------
extern "C" void kernel_launch(void* const* d_in, const int* in_sizes, int n_in,
                              void* d_out, int out_size, void* d_ws, size_t ws_size,
                              hipStream_t stream)
{
    const float* x   = (const float*)d_in[0];
    const float* Wm  = (const float*)d_in[1];
    const float* bm  = (const float*)d_in[2];
    const float* Wih = (const float*)d_in[3];
    const float* Whh = (const float*)d_in[4];
    const float* bih = (const float*)d_in[5];
    const float* bhh = (const float*)d_in[6];

    char* ws = (char*)d_ws;
    bf16_t* Wrz = (bf16_t*)(ws);                 // 131072 B
    bf16_t* Win = (bf16_t*)(ws + 131072);        //  32768 B
    bf16_t* Whn = (bf16_t*)(ws + 163840);        //  32768 B
    bf16_t* WmP = (bf16_t*)(ws + 196608);        //  16384 B
    float*  bcp = (float*) (ws + 212992);        //   2048 B

    pack_kernel<<<418, 256, 0, stream>>>(Wm, Wih, Whh, bih, bhh, Wrz, Win, Whn, WmP, bcp);
    gru_all<<<256, 512, 0, stream>>>(x, (float*)d_out, Wrz, Win, Whn, WmP, bcp, bm);
}